// Round 19
// baseline (210.630 us; speedup 1.0000x reference)
//
#include <hip/hip_runtime.h>
#include <cmath>

typedef float f32x4 __attribute__((ext_vector_type(4)));
typedef float f32x16 __attribute__((ext_vector_type(16)));
typedef __bf16 bf16x8 __attribute__((ext_vector_type(8)));

#define DEV static __device__ __forceinline__

DEV unsigned short f2bf(float f) {
  unsigned int u = __builtin_bit_cast(unsigned int, f);
  u += 0x7FFFu + ((u >> 16) & 1u);
  return (unsigned short)(u >> 16);
}
DEV float bf2f(unsigned short h) {
  unsigned int u = ((unsigned int)h) << 16;
  return __builtin_bit_cast(float, u);
}
DEV unsigned int cvtpk(float lo, float hi) {  // [bf16(lo) | bf16(hi)<<16], HW RNE
  unsigned int r;
  asm("v_cvt_pk_bf16_f32 %0, %1, %2" : "=v"(r) : "v"(lo), "v"(hi));
  return r;
}
DEV f32x4 mfma16(bf16x8 a, bf16x8 b, f32x4 c) {
  return __builtin_amdgcn_mfma_f32_16x16x32_bf16(a, b, c, 0, 0, 0);
}
DEV f32x16 mfma32(bf16x8 a, bf16x8 b, f32x16 c) {
  return __builtin_amdgcn_mfma_f32_32x32x16_bf16(a, b, c, 0, 0, 0);
}
// async global->LDS, 16B per lane; lds dest = wave-uniform base (+ lane*16 by HW)
DEV void dma16(const void* g, void* l) {
  __builtin_amdgcn_global_load_lds(
      (const __attribute__((address_space(1))) void*)(uintptr_t)g,
      (__attribute__((address_space(3))) void*)(unsigned int)(uintptr_t)l,
      16, 0, 0);
}

constexpr int T_SEQ = 2048;

// ---- fused prep: [0,8192) x->bf16 swizzled; [8192,8704) rope table;
//      [8704,11264) the three weight transposes (fp32 RxC -> bf16 CxR)
__global__ __launch_bounds__(256) void prep_all(const float4* __restrict__ in,
                                                ushort* __restrict__ out,
                                                float2* __restrict__ rope,
                                                const float* __restrict__ Wq,
                                                const float* __restrict__ Wkv,
                                                const float* __restrict__ Wo,
                                                ushort* __restrict__ wqkv,
                                                ushort* __restrict__ wot) {
  __shared__ ushort tile[64][65];
  const int bx = blockIdx.x;
  if (bx < 8192) {
    int i = bx * 256 + threadIdx.x;  // < 2097152
    float4 v = in[i];
    unsigned int lo = (unsigned int)f2bf(v.x) | ((unsigned int)f2bf(v.y) << 16);
    unsigned int hi = (unsigned int)f2bf(v.z) | ((unsigned int)f2bf(v.w) << 16);
    int row = i >> 9;  // 512 float4 per 2048-elem row
    int e = (i * 4) & 2047;
    size_t o = ((size_t)row << 11) + (size_t)(e ^ ((row & 7) << 3));
    *(uint2*)(out + o) = make_uint2(lo, hi);
  } else if (bx < 8704) {
    int gid = (bx - 8192) * 256 + threadIdx.x;  // < 131072 = T_SEQ*64
    int t = gid >> 6, i = gid & 63;
    double inv = pow(10000.0, -((double)(2 * i)) / 128.0);
    double wl = 6.283185307179586 / inv;
    double gm = (4096.0 - wl) / (4096.0 - 128.0);
    gm = gm < 0.0 ? 0.0 : (gm > 1.0 ? 1.0 : gm);
    float f = (float)(gm * inv + (1.0 - gm) * inv * 0.25);
    float th = (float)t * f;
    float s, c;
    sincosf(th, &s, &c);
    rope[gid] = make_float2(c, s);
  } else {
    const int l = bx - 8704;        // < 2560 = 80 x 32
    const int bxl0 = l % 80, by = l / 80;
    const float* src;
    ushort* dst;
    int C, bxl;
    if (bxl0 < 32) {
      src = Wq; dst = wqkv; C = 2048; bxl = bxl0;
    } else if (bxl0 < 48) {
      src = Wkv; dst = wqkv + (size_t)2048 * 2048; C = 1024; bxl = bxl0 - 32;
    } else {
      src = Wo; dst = wot; C = 2048; bxl = bxl0 - 48;
    }
    const int R = 2048;  // K-stride of the transposed output
    int c0 = bxl * 64, r0 = by * 64;
    int j = threadIdx.x & 63, i0 = threadIdx.x >> 6;
#pragma unroll
    for (int ii = 0; ii < 16; ++ii) {
      int i = i0 + ii * 4;
      tile[i][j] = f2bf(src[(size_t)(r0 + i) * C + c0 + j]);
    }
    __syncthreads();
#pragma unroll
    for (int ii = 0; ii < 16; ++ii) {
      int jr = i0 + ii * 4;
      dst[(size_t)(c0 + jr) * R + ((r0 + j) ^ ((jr & 7) << 3))] = tile[j][jr];
    }
  }
}

// ------------- bf16 GEMM, 32x32x16 MFMA, phase-split, 2 blocks/CU, XCD-chunked.
// 512 threads = 8 waves in 4M x 2N grid; wave-tile = 32 x (BN/2) = 1 M-frag x
// NF N-frags of 32x32. Per K-tile (64 = 4 k-steps): NF phases of {ds_read
// B-frag k-steps || stage chunk -> barrier -> 4 mfma32 (setprio)}; A-frags
// (4 b128) hoisted at phase 0. ~17% fewer MFMA issue cycles than 16x16 at
// identical LDS/DMA traffic. Fragment maps HW-validated in attn (R6):
// A/B: row=lane&31, k=8*(lane>>5)+e; D: col=lane&31, row=(r&3)+8*(r>>2)+4*hi.
template <int BM, int BN, int OUT_BF16>
__global__ __launch_bounds__(512) void gemm256(const ushort* __restrict__ A,
                                               const ushort* __restrict__ Bt,
                                               void* __restrict__ Cv,
                                               int M, int N, int K) {
  constexpr int NF = BN / 64;          // N-frags per wave = phases (3 or 2)
  constexpr int ADMA = BM / 64;        // A dma16 per wave per K-tile (2)
  constexpr int BDMA = BN / 64;        // B dma16 per wave per K-tile (3 or 2)
  constexpr int BC0 = (BDMA + 1) / 2;  // B lines staged in phase 0
  __shared__ ushort lA[2][BM * 64];
  __shared__ ushort lB[2][BN * 64];
  const int tid = threadIdx.x, lane = tid & 63, w = tid >> 6;
  const int hi = lane >> 5, l31 = lane & 31;
  const int wm = (w >> 1) * 32;        // 4 M-groups of 32 rows
  const int wn = (w & 1) * (BN / 2);   // 2 N-halves
  const int bid = blockIdx.x;                       // 512 blocks
  const int f = ((bid & 7) << 6) + (bid >> 3);      // XCD-chunked remap
  const int pm = f >> 4, pn = f & 15;               // 32 x 16 logical grid
  const int m0 = pm * BM, n0 = pn * BN;

  f32x16 acc[NF] = {};

  const size_t K2 = (size_t)K * 2;
  const char* Ab = (const char*)A + (size_t)m0 * K2;
  const char* Bb = (const char*)Bt + (size_t)n0 * K2;
  const int srb = lane >> 3;        // sub-row within an 8-row dma line
  const int scb = (lane & 7) * 16;  // byte col within 128B row

  auto stageA = [&](int t, int bi) {
#pragma unroll
    for (int ii = 0; ii < ADMA; ++ii) {
      const int ar = w * (BM / 8) + ii * 8;
      dma16(Ab + (size_t)(ar + srb) * K2 + (size_t)t * 128 + scb,
            (char*)lA[bi] + ar * 128);
    }
  };
  auto stageB = [&](int t, int bi, int l0, int cnt) {
    for (int ii = l0; ii < l0 + cnt; ++ii) {
      const int br = w * (BN / 8) + ii * 8;
      dma16(Bb + (size_t)(br + srb) * K2 + (size_t)t * 128 + scb,
            (char*)lB[bi] + br * 128);
    }
  };

  stageA(0, 0);
  stageB(0, 0, 0, BDMA);
  const int nkt = K >> 6;

  asm volatile("s_waitcnt vmcnt(0)" ::: "memory");
  __builtin_amdgcn_s_barrier();

  const int arow = wm + l31;
  const int aswz = (arow & 7) << 4;

  for (int t = 0; t < nkt; ++t) {
    const int cur = t & 1;
    const char* lAc = (const char*)lA[cur];
    const char* lBc = (const char*)lB[cur];
    const bool pre = (t + 1 < nkt);

    bf16x8 af[4];
#pragma unroll
    for (int ph = 0; ph < NF; ++ph) {
      if (ph == 0) {
#pragma unroll
        for (int c = 0; c < 4; ++c)
          af[c] = *(const bf16x8*)(lAc + arow * 128 + ((c * 32 + 16 * hi) ^ aswz));
      }
      bf16x8 bfr[4];
      const int brow = wn + ph * 32 + l31;
      const int bswz = (brow & 7) << 4;
#pragma unroll
      for (int c = 0; c < 4; ++c)
        bfr[c] = *(const bf16x8*)(lBc + brow * 128 + ((c * 32 + 16 * hi) ^ bswz));
      if (pre) {  // issue next tile's loads early (phases 0-1 only)
        if (ph == 0) {
          stageA(t + 1, cur ^ 1);
          stageB(t + 1, cur ^ 1, 0, BC0);
        } else if (ph == 1) {
          stageB(t + 1, cur ^ 1, BC0, BDMA - BC0);
        }
      }
      __builtin_amdgcn_s_barrier();
      __builtin_amdgcn_sched_barrier(0);
      __builtin_amdgcn_s_setprio(1);
#pragma unroll
      for (int c = 0; c < 4; ++c) acc[ph] = mfma32(af[c], bfr[c], acc[ph]);
      __builtin_amdgcn_s_setprio(0);
    }
    __builtin_amdgcn_sched_barrier(0);
    asm volatile("s_waitcnt vmcnt(0)" ::: "memory");  // next tile landed (issued phases ago)
    __builtin_amdgcn_s_barrier();
  }

  // epilogue: D col = n (lane&31), row = (r&3) + 8*(r>>2) + 4*hi
  if (OUT_BF16) {
    ushort* C = (ushort*)Cv;
#pragma unroll
    for (int nf = 0; nf < NF; ++nf) {
      const int n = n0 + wn + nf * 32 + l31;
#pragma unroll
      for (int r = 0; r < 16; ++r) {
        const int m = m0 + wm + (r & 3) + 8 * (r >> 2) + 4 * hi;
        C[(size_t)m * N + n] = f2bf(acc[nf][r]);
      }
    }
  } else {
    float* C = (float*)Cv;
#pragma unroll
    for (int nf = 0; nf < NF; ++nf) {
      const int n = n0 + wn + nf * 32 + l31;
#pragma unroll
      for (int r = 0; r < 16; ++r) {
        const int m = m0 + wm + (r & 3) + 8 * (r >> 2) + 4 * hi;
        C[(size_t)m * N + n] = acc[nf][r];
      }
    }
  }
}

// ---- fused post-projection transform: blocks [0,20480) = RMSNorm + YaRN
// RoPE on q,k (Q scaled by attn_scale*log2e, exp2-domain softmax); blocks
// [20480,20992) = V transpose (b,t,g,d)->(b,g,d,t), pre-swizzled rows.
__global__ __launch_bounds__(256) void normrope_tv(const ushort* __restrict__ qkv,
                                                   const float* __restrict__ qw,
                                                   const float* __restrict__ kw,
                                                   const float2* __restrict__ rope,
                                                   ushort* __restrict__ qout,
                                                   ushort* __restrict__ kout,
                                                   ushort* __restrict__ vt,
                                                   float q_scale) {
  __shared__ ushort tile[64][65];
  const int bx = blockIdx.x;
  if (bx < 20480) {
    const int w = threadIdx.x >> 6, lane = threadIdx.x & 63;
    const int vi = bx * 4 + w;
    const ushort* src;
    const float* wt;
    ushort* dst;
    float extra;
    int t, bb;
    if (vi < 65536) {
      int row = vi >> 4, H = vi & 15;
      bb = row >> 11;
      t = row & 2047;
      src = qkv + (size_t)row * 3072 + H * 128 + lane * 2;
      wt = qw;
      extra = q_scale;
      dst = qout + ((size_t)(bb * 16 + H) * T_SEQ + t) * 128 + lane * 2;  // linear
    } else {
      int vi2 = vi - 65536;
      int row = vi2 >> 2, gg = vi2 & 3;
      bb = row >> 11;
      t = row & 2047;
      src = qkv + (size_t)row * 3072 + 2048 + gg * 128 + lane * 2;
      wt = kw;
      extra = 1.f;
      dst = kout + ((size_t)(bb * 4 + gg) * T_SEQ + t) * 128 +
            ((lane * 2) ^ ((t & 7) << 3));  // pre-swizzled for DMA staging
    }
    float x0 = bf2f(src[0]), x1 = bf2f(src[1]);
    float ss = x0 * x0 + x1 * x1;
#pragma unroll
    for (int d = 1; d < 64; d <<= 1) ss += __shfl_xor(ss, d, 64);
    float sc = rsqrtf(ss * (1.f / 128.f) + 1.1920929e-7f);
    float w0 = wt[lane * 2], w1 = wt[lane * 2 + 1];
    float xn0 = x0 * sc * w0, xn1 = x1 * sc * w1;
    float p0 = __shfl_xor(xn0, 32, 64), p1 = __shfl_xor(xn1, 32, 64);
    float r0 = lane < 32 ? -p0 : p0;
    float r1 = lane < 32 ? -p1 : p1;
    int i0 = (lane * 2) & 63;
    float2 cs0 = rope[t * 64 + i0];
    float2 cs1 = rope[t * 64 + i0 + 1];
    float o0 = (xn0 * cs0.x + r0 * cs0.y) * extra;
    float o1 = (xn1 * cs1.x + r1 * cs1.y) * extra;
    unsigned int pkv = (unsigned int)f2bf(o0) | ((unsigned int)f2bf(o1) << 16);
    *(unsigned int*)dst = pkv;
  } else {
    const int l = bx - 20480;       // < 512 = 32 x 16
    int t0 = (l & 31) * 64;
    int y = l >> 5;                 // ((b*4+g)*2 + dh)
    int dh = y & 1, bg = y >> 1;
    int bb = bg >> 2, g = bg & 3;
    int j = threadIdx.x & 63, i0 = threadIdx.x >> 6;
#pragma unroll
    for (int ii = 0; ii < 16; ++ii) {
      int i = i0 + ii * 4;
      tile[i][j] = qkv[(size_t)(bb * T_SEQ + t0 + i) * 3072 + 2560 + g * 128 + dh * 64 + j];
    }
    __syncthreads();
#pragma unroll
    for (int ii = 0; ii < 16; ++ii) {
      int jr = i0 + ii * 4;
      vt[((size_t)bg * 128 + dh * 64 + jr) * T_SEQ + ((t0 + j) ^ ((jr & 7) << 3))] = tile[j][jr];
    }
  }
}

// ----------------------------------------------------------- flash attention
// R5-verified (77.2 us): 128-row Q-tiles, 4 waves x 32 rows/wave, 512 blocks
// (complement qt pairs), double-buffered K/V DMA with counted vmcnt(8), exp2
// softmax, cvt_pk bf16 packing, P through per-wave-private LDS.
__global__ __launch_bounds__(256, 2) void attn_fwd(const ushort* __restrict__ qh,
                                                   const ushort* __restrict__ kh,
                                                   const ushort* __restrict__ vt,
                                                   ushort* __restrict__ o) {
  const int f = blockIdx.x;              // 512 blocks
  const int half = f >> 8, c = f & 255;
  const int kk = c >> 5, bh = c & 31;
  const int qt = half ? kk : (15 - kk);  // blocks c and c+256 complement, same bh
  const int b = bh >> 4, H = bh & 15;
  const int g = H & 3;
  const int tid = threadIdx.x, lane = tid & 63, w = tid >> 6;  // w in 0..3
  const int wrow0 = qt * 128 + w * 32;

  __shared__ ushort lK[2][64 * 128];    // 2 x 16KB swizzled, rows = kv
  __shared__ ushort lV[2][128 * 64];    // 2 x 16KB swizzled, rows = d (V^T)
  __shared__ ushort lP[4 * 32 * 64];    // 16KB, per-wave private 32x64

  bf16x8 qf[2][4];
#pragma unroll
  for (int mt = 0; mt < 2; ++mt) {
    const ushort* qb = qh + ((size_t)(b * 16 + H) * T_SEQ + wrow0 + mt * 16 + (lane & 15)) * 128 +
                       ((lane >> 4) << 3);
#pragma unroll
    for (int kc = 0; kc < 4; ++kc) qf[mt][kc] = *(const bf16x8*)(qb + kc * 32);
  }

  f32x4 oacc[2][8] = {};
  float mrow[2] = {-INFINITY, -INFINITY};
  float lrow[2] = {0.f, 0.f};

  const char* kpl = (const char*)(kh + (size_t)(b * 4 + g) * T_SEQ * 128);
  const char* vpl = (const char*)(vt + (size_t)(b * 4 + g) * 128 * T_SEQ);

  // per wave: 4 dma16 for K (rows 16w..16w+15) + 4 for V (d-rows 32w..32w+31)
  auto stage = [&](int j, int bi) {
#pragma unroll
    for (int ii = 0; ii < 4; ++ii) {
      const int off = w * 4096 + ii * 1024;
      dma16(kpl + (size_t)j * 16384 + off + lane * 16, (char*)lK[bi] + off);
      const int vrow = w * 32 + ii * 8 + (lane >> 3);
      dma16(vpl + (size_t)vrow * (T_SEQ * 2) + j * 128 + (lane & 7) * 16,
            (char*)lV[bi] + off);
    }
  };

  stage(0, 0);

  const int rsel = ((lane >> 4) << 2);   // C-fragment row base within 16-row tile

  const int jmax = 2 * qt + 1;
  for (int j = 0; j <= jmax; ++j) {
    const int cur = j & 1;
    if (j < jmax) {
      stage(j + 1, cur ^ 1);                            // prefetch next tile
      asm volatile("s_waitcnt vmcnt(8)" ::: "memory");  // tile j landed, j+1 in flight
    } else {
      asm volatile("s_waitcnt vmcnt(0)" ::: "memory");
    }
    __builtin_amdgcn_s_barrier();
    __builtin_amdgcn_sched_barrier(0);

    // S^T = K Q^T (per wave: 64 kv x 32 q); kf read once, used for both mt
    f32x4 s[2][4];
#pragma unroll
    for (int nt = 0; nt < 4; ++nt) {
      bf16x8 kf[4];
      int krow = nt * 16 + (lane & 15);
#pragma unroll
      for (int kc = 0; kc < 4; ++kc) {
        int byo = kc * 64 + ((lane >> 4) << 4);
        kf[kc] = *(const bf16x8*)((const char*)lK[cur] + krow * 256 + (byo ^ ((krow & 7) << 4)));
      }
#pragma unroll
      for (int mt = 0; mt < 2; ++mt) {
        f32x4 a = {0.f, 0.f, 0.f, 0.f};
#pragma unroll
        for (int kc = 0; kc < 4; ++kc) a = mfma16(kf[kc], qf[mt][kc], a);
        s[mt][nt] = a;
      }
    }

    // causal mask: only tiles crossing this wave's 32 rows
    if (j * 64 + 63 > wrow0) {
#pragma unroll
      for (int mt = 0; mt < 2; ++mt) {
        int qrow = wrow0 + mt * 16 + (lane & 15);
#pragma unroll
        for (int nt = 0; nt < 4; ++nt)
#pragma unroll
          for (int jj = 0; jj < 4; ++jj) {
            int col = j * 64 + nt * 16 + rsel + jj;
            if (col > qrow) s[mt][nt][jj] = -3.0e38f;
          }
      }
    }

    // per-row max: in-lane over 16 kv + 2-step cross-group reduce
    float pmx[2], mn[2];
#pragma unroll
    for (int mt = 0; mt < 2; ++mt) {
      float a0 = fmaxf(fmaxf(s[mt][0][0], s[mt][0][1]), fmaxf(s[mt][0][2], s[mt][0][3]));
      float a1 = fmaxf(fmaxf(s[mt][1][0], s[mt][1][1]), fmaxf(s[mt][1][2], s[mt][1][3]));
      float a2 = fmaxf(fmaxf(s[mt][2][0], s[mt][2][1]), fmaxf(s[mt][2][2], s[mt][2][3]));
      float a3 = fmaxf(fmaxf(s[mt][3][0], s[mt][3][1]), fmaxf(s[mt][3][2], s[mt][3][3]));
      float p = fmaxf(fmaxf(a0, a1), fmaxf(a2, a3));
      p = fmaxf(p, __shfl_xor(p, 16, 64));
      p = fmaxf(p, __shfl_xor(p, 32, 64));
      pmx[mt] = p;
      mn[mt] = mrow[mt];
    }

    bool ok = (pmx[0] <= mrow[0] + 11.5417f) && (pmx[1] <= mrow[1] + 11.5417f);
    if (!__all(ok)) {  // defer-max: rescale only on real growth (bound 2^11.5=e^8)
#pragma unroll
      for (int mt = 0; mt < 2; ++mt) {
        mn[mt] = fmaxf(mrow[mt], pmx[mt]);
        float rsc = exp2f(mrow[mt] - mn[mt]);
        mrow[mt] = mn[mt];
        lrow[mt] *= rsc;
        float rr0 = __shfl(rsc, rsel + 0, 64);
        float rr1 = __shfl(rsc, rsel + 1, 64);
        float rr2 = __shfl(rsc, rsel + 2, 64);
        float rr3 = __shfl(rsc, rsel + 3, 64);
#pragma unroll
        for (int dt = 0; dt < 8; ++dt) {
          oacc[mt][dt][0] *= rr0; oacc[mt][dt][1] *= rr1;
          oacc[mt][dt][2] *= rr2; oacc[mt][dt][3] *= rr3;
        }
      }
    }

    // P = exp2(S - mn), in-lane sum, cvt_pk pack to LDS (b64 per nt)
#pragma unroll
    for (int mt = 0; mt < 2; ++mt) {
      float ps = 0.f;
      int prow = mt * 16 + (lane & 15);
      char* pbase = (char*)lP + w * 4096 + prow * 128;
      int swz = (prow & 7) << 4;
#pragma unroll
      for (int nt = 0; nt < 4; ++nt) {
        float p0 = exp2f(s[mt][nt][0] - mn[mt]);
        float p1 = exp2f(s[mt][nt][1] - mn[mt]);
        float p2 = exp2f(s[mt][nt][2] - mn[mt]);
        float p3 = exp2f(s[mt][nt][3] - mn[mt]);
        ps += (p0 + p1) + (p2 + p3);
        int pcb = (nt * 32 + ((lane >> 4) << 3)) ^ swz;
        *(uint2*)(pbase + pcb) = make_uint2(cvtpk(p0, p1), cvtpk(p2, p3));
      }
      ps += __shfl_xor(ps, 16, 64);
      ps += __shfl_xor(ps, 32, 64);
      lrow[mt] += ps;
    }

    // O += P V   (P per-wave private; vf read once, used for both mt)
#pragma unroll
    for (int kc2 = 0; kc2 < 2; ++kc2) {
      bf16x8 pa[2];
#pragma unroll
      for (int mt = 0; mt < 2; ++mt) {
        int prow = mt * 16 + (lane & 15);
        int pbo = kc2 * 64 + ((lane >> 4) << 4);
        pa[mt] = *(const bf16x8*)((char*)lP + w * 4096 + prow * 128 + (pbo ^ ((prow & 7) << 4)));
      }
#pragma unroll
      for (int dt = 0; dt < 8; ++dt) {
        int vrow = dt * 16 + (lane & 15);
        int vbo = kc2 * 64 + ((lane >> 4) << 4);
        bf16x8 vf = *(const bf16x8*)((const char*)lV[cur] + vrow * 128 + (vbo ^ ((vrow & 7) << 4)));
#pragma unroll
        for (int mt = 0; mt < 2; ++mt) oacc[mt][dt] = mfma16(pa[mt], vf, oacc[mt][dt]);
      }
    }

    __builtin_amdgcn_sched_barrier(0);
    __builtin_amdgcn_s_barrier();   // all waves done with buf[cur] before stage(j+2)
  }

  // write O (b, t, H*128+d) bf16, pre-swizzled rows for the Wo GEMM's DMA
#pragma unroll
  for (int mt = 0; mt < 2; ++mt) {
    float linv = 1.f / lrow[mt];
    float iv0 = __shfl(linv, rsel + 0, 64);
    float iv1 = __shfl(linv, rsel + 1, 64);
    float iv2 = __shfl(linv, rsel + 2, 64);
    float iv3 = __shfl(linv, rsel + 3, 64);
    int row = wrow0 + mt * 16 + rsel;
#pragma unroll
    for (int dt = 0; dt < 8; ++dt) {
      int col = H * 128 + dt * 16 + (lane & 15);
      o[(size_t)(b * T_SEQ + row + 0) * 2048 + (col ^ (((row + 0) & 7) << 3))] =
          f2bf(oacc[mt][dt][0] * iv0);
      o[(size_t)(b * T_SEQ + row + 1) * 2048 + (col ^ (((row + 1) & 7) << 3))] =
          f2bf(oacc[mt][dt][1] * iv1);
      o[(size_t)(b * T_SEQ + row + 2) * 2048 + (col ^ (((row + 2) & 7) << 3))] =
          f2bf(oacc[mt][dt][2] * iv2);
      o[(size_t)(b * T_SEQ + row + 3) * 2048 + (col ^ (((row + 3) & 7) << 3))] =
          f2bf(oacc[mt][dt][3] * iv3);
    }
  }
}

// ---------------------------------------------------------------------------
extern "C" void kernel_launch(void* const* d_in, const int* in_sizes, int n_in,
                              void* d_out, int out_size, void* d_ws, size_t ws_size,
                              hipStream_t stream) {
  (void)in_sizes; (void)n_in; (void)out_size; (void)ws_size;
  const float* x = (const float*)d_in[0];
  const float* Wq = (const float*)d_in[1];
  const float* Wkv = (const float*)d_in[2];
  const float* Wo = (const float*)d_in[3];
  const float* qnw = (const float*)d_in[4];
  const float* knw = (const float*)d_in[5];
  float* out = (float*)d_out;
  char* ws = (char*)d_ws;

  ushort* xb = (ushort*)(ws);                 // 16,777,216 B (bf16 x, swizzled)
  ushort* wqkv = (ushort*)(ws + 16777216);    // 12,582,912 B (Wq^T ++ Wkv^T, swizzled)
  ushort* wot = (ushort*)(ws + 29360128);     //  8,388,608 B (Wo^T, swizzled)
  ushort* qkvraw = (ushort*)(ws + 37748736);  // 25,165,824 B (4096 x 3072, linear)
  ushort* kh = (ushort*)(ws + 62914560);      //  4,194,304 B (swizzled)
  ushort* vtp = (ushort*)(ws + 67108864);     //  4,194,304 B (swizzled V^T)
  float2* rope = (float2*)(ws + 71303168);    //  1,048,576 B (total 72,351,744)
  ushort* qh = xb;        // alias: xb dead after projection GEMM
  ushort* attnb = qkvraw; // alias: qkvraw dead after norm_rope + tv

  float attn_scale = 1.0f / ((0.1f * logf(4.0f) + 1.0f) * sqrtf(128.0f));
  float q_scale = attn_scale * 1.44269504f;   // exp2-domain softmax

  prep_all<<<11264, 256, 0, stream>>>((const float4*)x, xb, rope, Wq, Wkv, Wo, wqkv, wot);
  gemm256<128, 192, 1><<<512, 512, 0, stream>>>(xb, wqkv, qkvraw, 4096, 3072, 2048);
  normrope_tv<<<20992, 256, 0, stream>>>(qkvraw, qnw, knw, rope, qh, kh, vtp, q_scale);
  attn_fwd<<<512, 256, 0, stream>>>(qh, kh, vtp, attnb);
  gemm256<128, 128, 0><<<512, 512, 0, stream>>>(attnb, wot, out, 4096, 2048, 2048);
}

// Round 20
// 195.062 us; speedup vs baseline: 1.0798x; 1.0798x over previous
//
#include <hip/hip_runtime.h>
#include <cmath>

typedef float f32x4 __attribute__((ext_vector_type(4)));
typedef __bf16 bf16x8 __attribute__((ext_vector_type(8)));

#define DEV static __device__ __forceinline__

DEV unsigned short f2bf(float f) {
  unsigned int u = __builtin_bit_cast(unsigned int, f);
  u += 0x7FFFu + ((u >> 16) & 1u);
  return (unsigned short)(u >> 16);
}
DEV float bf2f(unsigned short h) {
  unsigned int u = ((unsigned int)h) << 16;
  return __builtin_bit_cast(float, u);
}
DEV unsigned int cvtpk(float lo, float hi) {  // [bf16(lo) | bf16(hi)<<16], HW RNE
  unsigned int r;
  asm("v_cvt_pk_bf16_f32 %0, %1, %2" : "=v"(r) : "v"(lo), "v"(hi));
  return r;
}
DEV f32x4 mfma16(bf16x8 a, bf16x8 b, f32x4 c) {
  return __builtin_amdgcn_mfma_f32_16x16x32_bf16(a, b, c, 0, 0, 0);
}
// async global->LDS, 16B per lane; lds dest = wave-uniform base (+ lane*16 by HW)
DEV void dma16(const void* g, void* l) {
  __builtin_amdgcn_global_load_lds(
      (const __attribute__((address_space(1))) void*)(uintptr_t)g,
      (__attribute__((address_space(3))) void*)(unsigned int)(uintptr_t)l,
      16, 0, 0);
}

constexpr int T_SEQ = 2048;

// ---- fused prep: [0,8192) x->bf16 swizzled; [8192,8704) rope table;
//      [8704,11264) the three weight transposes (fp32 RxC -> bf16 CxR)
__global__ __launch_bounds__(256) void prep_all(const float4* __restrict__ in,
                                                ushort* __restrict__ out,
                                                float2* __restrict__ rope,
                                                const float* __restrict__ Wq,
                                                const float* __restrict__ Wkv,
                                                const float* __restrict__ Wo,
                                                ushort* __restrict__ wqkv,
                                                ushort* __restrict__ wot) {
  __shared__ ushort tile[64][65];
  const int bx = blockIdx.x;
  if (bx < 8192) {
    int i = bx * 256 + threadIdx.x;  // < 2097152
    float4 v = in[i];
    unsigned int lo = (unsigned int)f2bf(v.x) | ((unsigned int)f2bf(v.y) << 16);
    unsigned int hi = (unsigned int)f2bf(v.z) | ((unsigned int)f2bf(v.w) << 16);
    int row = i >> 9;  // 512 float4 per 2048-elem row
    int e = (i * 4) & 2047;
    size_t o = ((size_t)row << 11) + (size_t)(e ^ ((row & 7) << 3));
    *(uint2*)(out + o) = make_uint2(lo, hi);
  } else if (bx < 8704) {
    int gid = (bx - 8192) * 256 + threadIdx.x;  // < 131072 = T_SEQ*64
    int t = gid >> 6, i = gid & 63;
    double inv = pow(10000.0, -((double)(2 * i)) / 128.0);
    double wl = 6.283185307179586 / inv;
    double gm = (4096.0 - wl) / (4096.0 - 128.0);
    gm = gm < 0.0 ? 0.0 : (gm > 1.0 ? 1.0 : gm);
    float f = (float)(gm * inv + (1.0 - gm) * inv * 0.25);
    float th = (float)t * f;
    float s, c;
    sincosf(th, &s, &c);
    rope[gid] = make_float2(c, s);
  } else {
    const int l = bx - 8704;        // < 2560 = 80 x 32
    const int bxl0 = l % 80, by = l / 80;
    const float* src;
    ushort* dst;
    int C, bxl;
    if (bxl0 < 32) {
      src = Wq; dst = wqkv; C = 2048; bxl = bxl0;
    } else if (bxl0 < 48) {
      src = Wkv; dst = wqkv + (size_t)2048 * 2048; C = 1024; bxl = bxl0 - 32;
    } else {
      src = Wo; dst = wot; C = 2048; bxl = bxl0 - 48;
    }
    const int R = 2048;  // K-stride of the transposed output
    int c0 = bxl * 64, r0 = by * 64;
    int j = threadIdx.x & 63, i0 = threadIdx.x >> 6;
#pragma unroll
    for (int ii = 0; ii < 16; ++ii) {
      int i = i0 + ii * 4;
      tile[i][j] = f2bf(src[(size_t)(r0 + i) * C + c0 + j]);
    }
    __syncthreads();
#pragma unroll
    for (int ii = 0; ii < 16; ++ii) {
      int jr = i0 + ii * 4;
      dst[(size_t)(c0 + jr) * R + ((r0 + j) ^ ((jr & 7) << 3))] = tile[j][jr];
    }
  }
}

// ------------- bf16 GEMM, phase-split schedule, 2 blocks/CU, XCD-chunked:
// 1-D 512-block grid; f = (bid&7)*64 + bid>>3 gives each XCD a compact
// 4-pm x 16-pn region. 512 threads = 8 waves (2M x 4N). Per K-tile: NT
// phases of {ds_read B-frag || stage chunk -> barrier -> 8 MFMA (setprio)};
// A-frags hoisted at phase 0 (4 independent accumulator chains = ILP);
// next tile's loads issued in phases 0-1. Double-buffered LDS.
template <int BM, int BN, int OUT_BF16>
__global__ __launch_bounds__(512) void gemm256(const ushort* __restrict__ A,
                                               const ushort* __restrict__ Bt,
                                               void* __restrict__ Cv,
                                               int M, int N, int K) {
  constexpr int MT = BM / 32;     // M-frags per wave (4)
  constexpr int NT = BN / 64;     // N-frags per wave (3 or 2) = phases
  constexpr int ADMA = BM / 64;   // A dma16 per wave per K-tile (2)
  constexpr int BDMA = BN / 64;   // B dma16 per wave per K-tile (3 or 2)
  constexpr int BC0 = (BDMA + 1) / 2;  // B lines staged in phase 0
  __shared__ ushort lA[2][BM * 64];
  __shared__ ushort lB[2][BN * 64];
  const int tid = threadIdx.x, lane = tid & 63, w = tid >> 6;
  const int wm = (w >> 2) * (BM / 2);
  const int wn = (w & 3) * (BN / 4);
  const int bid = blockIdx.x;                       // 512 blocks
  const int f = ((bid & 7) << 6) + (bid >> 3);      // XCD-chunked remap
  const int pm = f >> 4, pn = f & 15;               // 32 x 16 logical grid
  const int m0 = pm * BM, n0 = pn * BN;

  f32x4 acc[MT][NT] = {};

  const size_t K2 = (size_t)K * 2;
  const char* Ab = (const char*)A + (size_t)m0 * K2;
  const char* Bb = (const char*)Bt + (size_t)n0 * K2;
  const int srb = lane >> 3;        // sub-row within an 8-row dma line
  const int scb = (lane & 7) * 16;  // byte col within 128B row

  auto stageA = [&](int t, int bi) {
#pragma unroll
    for (int ii = 0; ii < ADMA; ++ii) {
      const int ar = w * (BM / 8) + ii * 8;
      dma16(Ab + (size_t)(ar + srb) * K2 + (size_t)t * 128 + scb,
            (char*)lA[bi] + ar * 128);
    }
  };
  auto stageB = [&](int t, int bi, int l0, int cnt) {
    for (int ii = l0; ii < l0 + cnt; ++ii) {
      const int br = w * (BN / 8) + ii * 8;
      dma16(Bb + (size_t)(br + srb) * K2 + (size_t)t * 128 + scb,
            (char*)lB[bi] + br * 128);
    }
  };

  stageA(0, 0);
  stageB(0, 0, 0, BDMA);
  const int nkt = K >> 6;

  asm volatile("s_waitcnt vmcnt(0)" ::: "memory");
  __builtin_amdgcn_s_barrier();

  for (int t = 0; t < nkt; ++t) {
    const int cur = t & 1;
    const char* lAc = (const char*)lA[cur];
    const char* lBc = (const char*)lB[cur];
    const bool pre = (t + 1 < nkt);

    bf16x8 af[2][MT];
#pragma unroll
    for (int ph = 0; ph < NT; ++ph) {
      if (ph == 0) {
#pragma unroll
        for (int kk = 0; kk < 2; ++kk) {
          const int byo = kk * 64 + ((lane >> 4) << 4);
#pragma unroll
          for (int i = 0; i < MT; ++i) {
            int row = wm + i * 16 + (lane & 15);
            af[kk][i] = *(const bf16x8*)(lAc + row * 128 + (byo ^ ((row & 7) << 4)));
          }
        }
      }
      bf16x8 bfr[2];
#pragma unroll
      for (int kk = 0; kk < 2; ++kk) {
        const int byo = kk * 64 + ((lane >> 4) << 4);
        int row = wn + ph * 16 + (lane & 15);
        bfr[kk] = *(const bf16x8*)(lBc + row * 128 + (byo ^ ((row & 7) << 4)));
      }
      if (pre) {  // issue next tile's loads early (phases 0-1 only)
        if (ph == 0) {
          stageA(t + 1, cur ^ 1);
          stageB(t + 1, cur ^ 1, 0, BC0);
        } else if (ph == 1) {
          stageB(t + 1, cur ^ 1, BC0, BDMA - BC0);
        }
      }
      __builtin_amdgcn_s_barrier();
      __builtin_amdgcn_sched_barrier(0);
      __builtin_amdgcn_s_setprio(1);
#pragma unroll
      for (int kk = 0; kk < 2; ++kk)
#pragma unroll
        for (int i = 0; i < MT; ++i)
          acc[i][ph] = mfma16(af[kk][i], bfr[kk], acc[i][ph]);
      __builtin_amdgcn_s_setprio(0);
    }
    __builtin_amdgcn_sched_barrier(0);
    asm volatile("s_waitcnt vmcnt(0)" ::: "memory");  // next tile landed (issued phases ago)
    __builtin_amdgcn_s_barrier();
  }

  const int rr = (lane >> 4) << 2;
  const int cc = lane & 15;
  if (OUT_BF16) {
    ushort* C = (ushort*)Cv;
#pragma unroll
    for (int mt = 0; mt < MT; ++mt)
#pragma unroll
      for (int nt = 0; nt < NT; ++nt)
#pragma unroll
        for (int j = 0; j < 4; ++j) {
          int r = m0 + wm + mt * 16 + rr + j;
          int c = n0 + wn + nt * 16 + cc;
          C[(size_t)r * N + c] = f2bf(acc[mt][nt][j]);
        }
  } else {
    float* C = (float*)Cv;
#pragma unroll
    for (int mt = 0; mt < MT; ++mt)
#pragma unroll
      for (int nt = 0; nt < NT; ++nt)
#pragma unroll
        for (int j = 0; j < 4; ++j) {
          int r = m0 + wm + mt * 16 + rr + j;
          int c = n0 + wn + nt * 16 + cc;
          C[(size_t)r * N + c] = acc[mt][nt][j];
        }
  }
}

// ---- fused post-projection transform: blocks [0,20480) = RMSNorm + YaRN
// RoPE on q,k (Q scaled by attn_scale*log2e, exp2-domain softmax); blocks
// [20480,20992) = V transpose (b,t,g,d)->(b,g,d,t), pre-swizzled rows.
__global__ __launch_bounds__(256) void normrope_tv(const ushort* __restrict__ qkv,
                                                   const float* __restrict__ qw,
                                                   const float* __restrict__ kw,
                                                   const float2* __restrict__ rope,
                                                   ushort* __restrict__ qout,
                                                   ushort* __restrict__ kout,
                                                   ushort* __restrict__ vt,
                                                   float q_scale) {
  __shared__ ushort tile[64][65];
  const int bx = blockIdx.x;
  if (bx < 20480) {
    const int w = threadIdx.x >> 6, lane = threadIdx.x & 63;
    const int vi = bx * 4 + w;
    const ushort* src;
    const float* wt;
    ushort* dst;
    float extra;
    int t, bb;
    if (vi < 65536) {
      int row = vi >> 4, H = vi & 15;
      bb = row >> 11;
      t = row & 2047;
      src = qkv + (size_t)row * 3072 + H * 128 + lane * 2;
      wt = qw;
      extra = q_scale;
      dst = qout + ((size_t)(bb * 16 + H) * T_SEQ + t) * 128 + lane * 2;  // linear
    } else {
      int vi2 = vi - 65536;
      int row = vi2 >> 2, gg = vi2 & 3;
      bb = row >> 11;
      t = row & 2047;
      src = qkv + (size_t)row * 3072 + 2048 + gg * 128 + lane * 2;
      wt = kw;
      extra = 1.f;
      dst = kout + ((size_t)(bb * 4 + gg) * T_SEQ + t) * 128 +
            ((lane * 2) ^ ((t & 7) << 3));  // pre-swizzled for DMA staging
    }
    float x0 = bf2f(src[0]), x1 = bf2f(src[1]);
    float ss = x0 * x0 + x1 * x1;
#pragma unroll
    for (int d = 1; d < 64; d <<= 1) ss += __shfl_xor(ss, d, 64);
    float sc = rsqrtf(ss * (1.f / 128.f) + 1.1920929e-7f);
    float w0 = wt[lane * 2], w1 = wt[lane * 2 + 1];
    float xn0 = x0 * sc * w0, xn1 = x1 * sc * w1;
    float p0 = __shfl_xor(xn0, 32, 64), p1 = __shfl_xor(xn1, 32, 64);
    float r0 = lane < 32 ? -p0 : p0;
    float r1 = lane < 32 ? -p1 : p1;
    int i0 = (lane * 2) & 63;
    float2 cs0 = rope[t * 64 + i0];
    float2 cs1 = rope[t * 64 + i0 + 1];
    float o0 = (xn0 * cs0.x + r0 * cs0.y) * extra;
    float o1 = (xn1 * cs1.x + r1 * cs1.y) * extra;
    unsigned int pkv = (unsigned int)f2bf(o0) | ((unsigned int)f2bf(o1) << 16);
    *(unsigned int*)dst = pkv;
  } else {
    const int l = bx - 20480;       // < 512 = 32 x 16
    int t0 = (l & 31) * 64;
    int y = l >> 5;                 // ((b*4+g)*2 + dh)
    int dh = y & 1, bg = y >> 1;
    int bb = bg >> 2, g = bg & 3;
    int j = threadIdx.x & 63, i0 = threadIdx.x >> 6;
#pragma unroll
    for (int ii = 0; ii < 16; ++ii) {
      int i = i0 + ii * 4;
      tile[i][j] = qkv[(size_t)(bb * T_SEQ + t0 + i) * 3072 + 2560 + g * 128 + dh * 64 + j];
    }
    __syncthreads();
#pragma unroll
    for (int ii = 0; ii < 16; ++ii) {
      int jr = i0 + ii * 4;
      vt[((size_t)bg * 128 + dh * 64 + jr) * T_SEQ + ((t0 + j) ^ ((jr & 7) << 3))] = tile[j][jr];
    }
  }
}

// ----------------------------------------------------------- flash attention
// R5-verified (77.2 us): 128-row Q-tiles, 4 waves x 32 rows/wave, 512 blocks
// (complement qt pairs), double-buffered K/V DMA with counted vmcnt(8), exp2
// softmax, cvt_pk bf16 packing, P through per-wave-private LDS.
__global__ __launch_bounds__(256, 2) void attn_fwd(const ushort* __restrict__ qh,
                                                   const ushort* __restrict__ kh,
                                                   const ushort* __restrict__ vt,
                                                   ushort* __restrict__ o) {
  const int f = blockIdx.x;              // 512 blocks
  const int half = f >> 8, c = f & 255;
  const int kk = c >> 5, bh = c & 31;
  const int qt = half ? kk : (15 - kk);  // blocks c and c+256 complement, same bh
  const int b = bh >> 4, H = bh & 15;
  const int g = H & 3;
  const int tid = threadIdx.x, lane = tid & 63, w = tid >> 6;  // w in 0..3
  const int wrow0 = qt * 128 + w * 32;

  __shared__ ushort lK[2][64 * 128];    // 2 x 16KB swizzled, rows = kv
  __shared__ ushort lV[2][128 * 64];    // 2 x 16KB swizzled, rows = d (V^T)
  __shared__ ushort lP[4 * 32 * 64];    // 16KB, per-wave private 32x64

  bf16x8 qf[2][4];
#pragma unroll
  for (int mt = 0; mt < 2; ++mt) {
    const ushort* qb = qh + ((size_t)(b * 16 + H) * T_SEQ + wrow0 + mt * 16 + (lane & 15)) * 128 +
                       ((lane >> 4) << 3);
#pragma unroll
    for (int kc = 0; kc < 4; ++kc) qf[mt][kc] = *(const bf16x8*)(qb + kc * 32);
  }

  f32x4 oacc[2][8] = {};
  float mrow[2] = {-INFINITY, -INFINITY};
  float lrow[2] = {0.f, 0.f};

  const char* kpl = (const char*)(kh + (size_t)(b * 4 + g) * T_SEQ * 128);
  const char* vpl = (const char*)(vt + (size_t)(b * 4 + g) * 128 * T_SEQ);

  // per wave: 4 dma16 for K (rows 16w..16w+15) + 4 for V (d-rows 32w..32w+31)
  auto stage = [&](int j, int bi) {
#pragma unroll
    for (int ii = 0; ii < 4; ++ii) {
      const int off = w * 4096 + ii * 1024;
      dma16(kpl + (size_t)j * 16384 + off + lane * 16, (char*)lK[bi] + off);
      const int vrow = w * 32 + ii * 8 + (lane >> 3);
      dma16(vpl + (size_t)vrow * (T_SEQ * 2) + j * 128 + (lane & 7) * 16,
            (char*)lV[bi] + off);
    }
  };

  stage(0, 0);

  const int rsel = ((lane >> 4) << 2);   // C-fragment row base within 16-row tile

  const int jmax = 2 * qt + 1;
  for (int j = 0; j <= jmax; ++j) {
    const int cur = j & 1;
    if (j < jmax) {
      stage(j + 1, cur ^ 1);                            // prefetch next tile
      asm volatile("s_waitcnt vmcnt(8)" ::: "memory");  // tile j landed, j+1 in flight
    } else {
      asm volatile("s_waitcnt vmcnt(0)" ::: "memory");
    }
    __builtin_amdgcn_s_barrier();
    __builtin_amdgcn_sched_barrier(0);

    // S^T = K Q^T (per wave: 64 kv x 32 q); kf read once, used for both mt
    f32x4 s[2][4];
#pragma unroll
    for (int nt = 0; nt < 4; ++nt) {
      bf16x8 kf[4];
      int krow = nt * 16 + (lane & 15);
#pragma unroll
      for (int kc = 0; kc < 4; ++kc) {
        int byo = kc * 64 + ((lane >> 4) << 4);
        kf[kc] = *(const bf16x8*)((const char*)lK[cur] + krow * 256 + (byo ^ ((krow & 7) << 4)));
      }
#pragma unroll
      for (int mt = 0; mt < 2; ++mt) {
        f32x4 a = {0.f, 0.f, 0.f, 0.f};
#pragma unroll
        for (int kc = 0; kc < 4; ++kc) a = mfma16(kf[kc], qf[mt][kc], a);
        s[mt][nt] = a;
      }
    }

    // causal mask: only tiles crossing this wave's 32 rows
    if (j * 64 + 63 > wrow0) {
#pragma unroll
      for (int mt = 0; mt < 2; ++mt) {
        int qrow = wrow0 + mt * 16 + (lane & 15);
#pragma unroll
        for (int nt = 0; nt < 4; ++nt)
#pragma unroll
          for (int jj = 0; jj < 4; ++jj) {
            int col = j * 64 + nt * 16 + rsel + jj;
            if (col > qrow) s[mt][nt][jj] = -3.0e38f;
          }
      }
    }

    // per-row max: in-lane over 16 kv + 2-step cross-group reduce
    float pmx[2], mn[2];
#pragma unroll
    for (int mt = 0; mt < 2; ++mt) {
      float a0 = fmaxf(fmaxf(s[mt][0][0], s[mt][0][1]), fmaxf(s[mt][0][2], s[mt][0][3]));
      float a1 = fmaxf(fmaxf(s[mt][1][0], s[mt][1][1]), fmaxf(s[mt][1][2], s[mt][1][3]));
      float a2 = fmaxf(fmaxf(s[mt][2][0], s[mt][2][1]), fmaxf(s[mt][2][2], s[mt][2][3]));
      float a3 = fmaxf(fmaxf(s[mt][3][0], s[mt][3][1]), fmaxf(s[mt][3][2], s[mt][3][3]));
      float p = fmaxf(fmaxf(a0, a1), fmaxf(a2, a3));
      p = fmaxf(p, __shfl_xor(p, 16, 64));
      p = fmaxf(p, __shfl_xor(p, 32, 64));
      pmx[mt] = p;
      mn[mt] = mrow[mt];
    }

    bool ok = (pmx[0] <= mrow[0] + 11.5417f) && (pmx[1] <= mrow[1] + 11.5417f);
    if (!__all(ok)) {  // defer-max: rescale only on real growth (bound 2^11.5=e^8)
#pragma unroll
      for (int mt = 0; mt < 2; ++mt) {
        mn[mt] = fmaxf(mrow[mt], pmx[mt]);
        float rsc = exp2f(mrow[mt] - mn[mt]);
        mrow[mt] = mn[mt];
        lrow[mt] *= rsc;
        float rr0 = __shfl(rsc, rsel + 0, 64);
        float rr1 = __shfl(rsc, rsel + 1, 64);
        float rr2 = __shfl(rsc, rsel + 2, 64);
        float rr3 = __shfl(rsc, rsel + 3, 64);
#pragma unroll
        for (int dt = 0; dt < 8; ++dt) {
          oacc[mt][dt][0] *= rr0; oacc[mt][dt][1] *= rr1;
          oacc[mt][dt][2] *= rr2; oacc[mt][dt][3] *= rr3;
        }
      }
    }

    // P = exp2(S - mn), in-lane sum, cvt_pk pack to LDS (b64 per nt)
#pragma unroll
    for (int mt = 0; mt < 2; ++mt) {
      float ps = 0.f;
      int prow = mt * 16 + (lane & 15);
      char* pbase = (char*)lP + w * 4096 + prow * 128;
      int swz = (prow & 7) << 4;
#pragma unroll
      for (int nt = 0; nt < 4; ++nt) {
        float p0 = exp2f(s[mt][nt][0] - mn[mt]);
        float p1 = exp2f(s[mt][nt][1] - mn[mt]);
        float p2 = exp2f(s[mt][nt][2] - mn[mt]);
        float p3 = exp2f(s[mt][nt][3] - mn[mt]);
        ps += (p0 + p1) + (p2 + p3);
        int pcb = (nt * 32 + ((lane >> 4) << 3)) ^ swz;
        *(uint2*)(pbase + pcb) = make_uint2(cvtpk(p0, p1), cvtpk(p2, p3));
      }
      ps += __shfl_xor(ps, 16, 64);
      ps += __shfl_xor(ps, 32, 64);
      lrow[mt] += ps;
    }

    // O += P V   (P per-wave private; vf read once, used for both mt)
#pragma unroll
    for (int kc2 = 0; kc2 < 2; ++kc2) {
      bf16x8 pa[2];
#pragma unroll
      for (int mt = 0; mt < 2; ++mt) {
        int prow = mt * 16 + (lane & 15);
        int pbo = kc2 * 64 + ((lane >> 4) << 4);
        pa[mt] = *(const bf16x8*)((char*)lP + w * 4096 + prow * 128 + (pbo ^ ((prow & 7) << 4)));
      }
#pragma unroll
      for (int dt = 0; dt < 8; ++dt) {
        int vrow = dt * 16 + (lane & 15);
        int vbo = kc2 * 64 + ((lane >> 4) << 4);
        bf16x8 vf = *(const bf16x8*)((const char*)lV[cur] + vrow * 128 + (vbo ^ ((vrow & 7) << 4)));
#pragma unroll
        for (int mt = 0; mt < 2; ++mt) oacc[mt][dt] = mfma16(pa[mt], vf, oacc[mt][dt]);
      }
    }

    __builtin_amdgcn_sched_barrier(0);
    __builtin_amdgcn_s_barrier();   // all waves done with buf[cur] before stage(j+2)
  }

  // write O (b, t, H*128+d) bf16, pre-swizzled rows for the Wo GEMM's DMA
#pragma unroll
  for (int mt = 0; mt < 2; ++mt) {
    float linv = 1.f / lrow[mt];
    float iv0 = __shfl(linv, rsel + 0, 64);
    float iv1 = __shfl(linv, rsel + 1, 64);
    float iv2 = __shfl(linv, rsel + 2, 64);
    float iv3 = __shfl(linv, rsel + 3, 64);
    int row = wrow0 + mt * 16 + rsel;
#pragma unroll
    for (int dt = 0; dt < 8; ++dt) {
      int col = H * 128 + dt * 16 + (lane & 15);
      o[(size_t)(b * T_SEQ + row + 0) * 2048 + (col ^ (((row + 0) & 7) << 3))] =
          f2bf(oacc[mt][dt][0] * iv0);
      o[(size_t)(b * T_SEQ + row + 1) * 2048 + (col ^ (((row + 1) & 7) << 3))] =
          f2bf(oacc[mt][dt][1] * iv1);
      o[(size_t)(b * T_SEQ + row + 2) * 2048 + (col ^ (((row + 2) & 7) << 3))] =
          f2bf(oacc[mt][dt][2] * iv2);
      o[(size_t)(b * T_SEQ + row + 3) * 2048 + (col ^ (((row + 3) & 7) << 3))] =
          f2bf(oacc[mt][dt][3] * iv3);
    }
  }
}

// ---------------------------------------------------------------------------
extern "C" void kernel_launch(void* const* d_in, const int* in_sizes, int n_in,
                              void* d_out, int out_size, void* d_ws, size_t ws_size,
                              hipStream_t stream) {
  (void)in_sizes; (void)n_in; (void)out_size; (void)ws_size;
  const float* x = (const float*)d_in[0];
  const float* Wq = (const float*)d_in[1];
  const float* Wkv = (const float*)d_in[2];
  const float* Wo = (const float*)d_in[3];
  const float* qnw = (const float*)d_in[4];
  const float* knw = (const float*)d_in[5];
  float* out = (float*)d_out;
  char* ws = (char*)d_ws;

  ushort* xb = (ushort*)(ws);                 // 16,777,216 B (bf16 x, swizzled)
  ushort* wqkv = (ushort*)(ws + 16777216);    // 12,582,912 B (Wq^T ++ Wkv^T, swizzled)
  ushort* wot = (ushort*)(ws + 29360128);     //  8,388,608 B (Wo^T, swizzled)
  ushort* qkvraw = (ushort*)(ws + 37748736);  // 25,165,824 B (4096 x 3072, linear)
  ushort* kh = (ushort*)(ws + 62914560);      //  4,194,304 B (swizzled)
  ushort* vtp = (ushort*)(ws + 67108864);     //  4,194,304 B (swizzled V^T)
  float2* rope = (float2*)(ws + 71303168);    //  1,048,576 B (total 72,351,744)
  ushort* qh = xb;        // alias: xb dead after projection GEMM
  ushort* attnb = qkvraw; // alias: qkvraw dead after norm_rope + tv

  float attn_scale = 1.0f / ((0.1f * logf(4.0f) + 1.0f) * sqrtf(128.0f));
  float q_scale = attn_scale * 1.44269504f;   // exp2-domain softmax

  prep_all<<<11264, 256, 0, stream>>>((const float4*)x, xb, rope, Wq, Wkv, Wo, wqkv, wot);
  gemm256<128, 192, 1><<<512, 512, 0, stream>>>(xb, wqkv, qkvraw, 4096, 3072, 2048);
  normrope_tv<<<20992, 256, 0, stream>>>(qkvraw, qnw, knw, rope, qh, kh, vtp, q_scale);
  attn_fwd<<<512, 256, 0, stream>>>(qh, kh, vtp, attnb);
  gemm256<128, 128, 0><<<512, 512, 0, stream>>>(attnb, wot, out, 4096, 2048, 2048);
}